// Round 1
// baseline (198.593 us; speedup 1.0000x reference)
//
#include <hip/hip_runtime.h>
#include <hip/hip_bf16.h>
#include <stdint.h>

typedef __bf16 bf16_t;
typedef bf16_t bf16x8 __attribute__((ext_vector_type(8)));
typedef float f32x4 __attribute__((ext_vector_type(4)));

// ---------------------------------------------------------------------------
// Kernel 1: transpose + cast  x(B,C,H,W) f32  ->  xt(B,H,W,C) bf16
// Block = (b, y) row; coalesced float4 reads, LDS transpose, coalesced writes.
// ---------------------------------------------------------------------------
__global__ __launch_bounds__(256) void k_transpose(const float* __restrict__ x,
                                                   bf16_t* __restrict__ xt) {
    __shared__ __align__(16) bf16_t tile[256][66];   // +2 pad: conflict-free
    const int b = blockIdx.x >> 6;
    const int y = blockIdx.x & 63;
    const int t = threadIdx.x;

    const float* src = x + ((size_t)(b * 256) * 64 + y) * 64;  // + c*4096 + x
    const int x4 = (t & 15) * 4;   // x position (float4 granules)
    const int cs = t >> 4;         // c sub-lane (16 c per pass)
    for (int cc = 0; cc < 256; cc += 16) {
        int c = cc + cs;
        float4 v = *(const float4*)(src + (size_t)c * 4096 + x4);
        tile[c][x4 + 0] = (bf16_t)v.x;
        tile[c][x4 + 1] = (bf16_t)v.y;
        tile[c][x4 + 2] = (bf16_t)v.z;
        tile[c][x4 + 3] = (bf16_t)v.w;
    }
    __syncthreads();
    // write: lane = c (contiguous bf16), loop over x
    bf16_t* dst = xt + ((size_t)(b * 64 + y) * 64) * 256 + t;
    for (int xx = 0; xx < 64; ++xx) {
        dst[(size_t)xx * 256] = tile[t][xx];
    }
}

// ---------------------------------------------------------------------------
// Kernel 2: pack weight (O,C,3,3) f32 -> Wp[kb][o][40] bf16 padded LDS image
// K order: kidx = kk*256 + c ; kb = kidx/32 (72 blocks of 32)
// Row stride 40 elems (80 B) so A-fragment ds_read_b128 is conflict-free.
// ---------------------------------------------------------------------------
__global__ __launch_bounds__(256) void k_pack_w(const float* __restrict__ w,
                                                bf16_t* __restrict__ Wp) {
    const int kb = blockIdx.x;     // 0..71
    const int o  = threadIdx.x;    // 0..255
    bf16_t* dst = Wp + (size_t)kb * 10240 + o * 40;   // 256*40 per kb
    const int kidx0 = kb * 32;
    const int kk = kidx0 >> 8;
    const int c0 = kidx0 & 255;
#pragma unroll
    for (int j = 0; j < 32; ++j) {
        dst[j] = (bf16_t)w[(size_t)(o * 256 + (c0 + j)) * 9 + kk];
    }
#pragma unroll
    for (int j = 32; j < 40; ++j) dst[j] = (bf16_t)0.0f;
}

// ---------------------------------------------------------------------------
// Kernel 3: fused deformable-sample + GEMM.
// Block = (b, h): N-tile = 64 pixels (full W row), M-tile = 256 (all O).
// 4 waves, each 64(O) x 64(px) via 4x4 tiles of mfma_f32_16x16x32_bf16.
// K-loop: 9 kk x 8 c-chunks of 32. W staged via global_load_lds; S-tile
// sampled from xt directly into LDS (im2col never hits HBM).
// ---------------------------------------------------------------------------
__global__ __launch_bounds__(256, 2) void k_dcn(
    const bf16_t* __restrict__ xt, const bf16_t* __restrict__ Wp,
    const float* __restrict__ coff, const float* __restrict__ cwm,
    const float* __restrict__ bias, float* __restrict__ out) {

    __shared__ __align__(16) bf16_t sW[256][40];  // 20480 B
    __shared__ __align__(16) bf16_t sS[64][40];   // 5120 B
    __shared__ float sCW[4][64];                  // corner weights (x mask)
    __shared__ int   sCA[4][64];                  // corner base elem offsets

    const int b = blockIdx.x >> 6;
    const int h = blockIdx.x & 63;
    const int t = threadIdx.x;
    const int wv = t >> 6;
    const int lane = t & 63;

    // staging indices: 4 threads per pixel, 8 channels each
    const int p  = t >> 2;
    const int cg = (t & 3) * 8;

    // MFMA fragment indices
    const int fr = lane & 15;
    const int kg = (lane >> 4) * 8;

    f32x4 acc[4][4] = {};

    for (int kk = 0; kk < 9; ++kk) {
        if (t < 64) {
            const int wpx = t;
            float oy = coff[((size_t)(b * 18 + kk * 2 + 0) * 64 + h) * 64 + wpx];
            float ox = coff[((size_t)(b * 18 + kk * 2 + 1) * 64 + h) * 64 + wpx];
            float m  = cwm [((size_t)(b * 9 + kk) * 64 + h) * 64 + wpx];
            float py = (float)(h - 1 + (kk / 3)) + oy;
            float px = (float)(wpx - 1 + (kk % 3)) + ox;
            float fy = floorf(py), fx = floorf(px);
            int y0 = (int)fy, x0 = (int)fx;
            int y1 = y0 + 1,  x1 = x0 + 1;
            float wy1 = py - fy, wx1 = px - fx;
            float wy0 = 1.0f - wy1, wx0 = 1.0f - wx1;
            bool vy0 = (y0 >= 0) && (y0 < 64), vy1 = (y1 >= 0) && (y1 < 64);
            bool vx0 = (x0 >= 0) && (x0 < 64), vx1 = (x1 >= 0) && (x1 < 64);
            int yc0 = min(max(y0, 0), 63), yc1 = min(max(y1, 0), 63);
            int xc0 = min(max(x0, 0), 63), xc1 = min(max(x1, 0), 63);
            const int base = b * 4096;
            sCW[0][wpx] = (vy0 && vx0) ? wy0 * wx0 * m : 0.0f;
            sCW[1][wpx] = (vy0 && vx1) ? wy0 * wx1 * m : 0.0f;
            sCW[2][wpx] = (vy1 && vx0) ? wy1 * wx0 * m : 0.0f;
            sCW[3][wpx] = (vy1 && vx1) ? wy1 * wx1 * m : 0.0f;
            sCA[0][wpx] = (base + yc0 * 64 + xc0) * 256;
            sCA[1][wpx] = (base + yc0 * 64 + xc1) * 256;
            sCA[2][wpx] = (base + yc1 * 64 + xc0) * 256;
            sCA[3][wpx] = (base + yc1 * 64 + xc1) * 256;
        }
        __syncthreads();

        for (int ci = 0; ci < 8; ++ci) {
            const int kb = kk * 8 + ci;
            // ---- stage W tile: async global->LDS, 5120 B per wave ----
            {
                const char* g = ((const char*)Wp) + (size_t)kb * 20480
                                + wv * 5120 + lane * 16;
                char* l = ((char*)&sW[0][0]) + wv * 5120;
#pragma unroll
                for (int i = 0; i < 5; ++i) {
                    __builtin_amdgcn_global_load_lds(
                        (const __attribute__((address_space(1))) unsigned int*)(g + i * 1024),
                        (__attribute__((address_space(3))) unsigned int*)(l + i * 1024),
                        16, 0, 0);
                }
            }
            // ---- stage S tile: bilinear sample 8 channels for pixel p ----
            {
                const int cbase = ci * 32 + cg;
                float s[8] = {0, 0, 0, 0, 0, 0, 0, 0};
#pragma unroll
                for (int k = 0; k < 4; ++k) {
                    float wgt = sCW[k][p];
                    bf16x8 v = *(const bf16x8*)(xt + sCA[k][p] + cbase);
#pragma unroll
                    for (int j = 0; j < 8; ++j) s[j] += wgt * (float)v[j];
                }
                bf16x8 ov;
#pragma unroll
                for (int j = 0; j < 8; ++j) ov[j] = (bf16_t)s[j];
                *(bf16x8*)&sS[p][cg] = ov;
            }
            __syncthreads();   // drains vmcnt (global_load_lds) + lds writes

            // ---- MFMA: wave computes o in [wv*64, wv*64+64), all 64 px ----
            {
                bf16x8 a[4], bf[4];
#pragma unroll
                for (int mt = 0; mt < 4; ++mt)
                    a[mt] = *(const bf16x8*)&sW[wv * 64 + mt * 16 + fr][kg];
#pragma unroll
                for (int nt = 0; nt < 4; ++nt)
                    bf[nt] = *(const bf16x8*)&sS[nt * 16 + fr][kg];
#pragma unroll
                for (int mt = 0; mt < 4; ++mt)
#pragma unroll
                    for (int nt = 0; nt < 4; ++nt)
                        acc[mt][nt] = __builtin_amdgcn_mfma_f32_16x16x32_bf16(
                            a[mt], bf[nt], acc[mt][nt], 0, 0, 0);
            }
            __syncthreads();   // protect sW/sS before next staging
        }
    }

    // ---- epilogue: D layout col=lane&15, row=(lane>>4)*4+r ----
    const int rowq = (lane >> 4) * 4;
#pragma unroll
    for (int mt = 0; mt < 4; ++mt) {
#pragma unroll
        for (int r = 0; r < 4; ++r) {
            const int o = wv * 64 + mt * 16 + rowq + r;
            const float bs = bias[o];
            float* op = out + ((size_t)(b * 256 + o) * 64 + h) * 64;
#pragma unroll
            for (int nt = 0; nt < 4; ++nt) {
                op[nt * 16 + fr] = acc[mt][nt][r] + bs;
            }
        }
    }
}

// ---------------------------------------------------------------------------
extern "C" void kernel_launch(void* const* d_in, const int* in_sizes, int n_in,
                              void* d_out, int out_size, void* d_ws, size_t ws_size,
                              hipStream_t stream) {
    const float* x    = (const float*)d_in[0];  // (8,256,64,64)
    const float* coff = (const float*)d_in[1];  // (8,18,64,64)
    const float* cwm  = (const float*)d_in[2];  // (8,9,64,64)
    const float* wgt  = (const float*)d_in[3];  // (256,256,3,3)
    const float* bias = (const float*)d_in[4];  // (256,)
    float* out = (float*)d_out;                 // (8,256,64,64)

    bf16_t* xt = (bf16_t*)d_ws;                 // 8*64*64*256 = 8,388,608 elems
    bf16_t* Wp = xt + (size_t)8 * 64 * 64 * 256; // 72*256*40 = 737,280 elems

    k_transpose<<<512, 256, 0, stream>>>(x, xt);
    k_pack_w   <<<72,  256, 0, stream>>>(wgt, Wp);
    k_dcn      <<<512, 256, 0, stream>>>(xt, Wp, coff, cwm, bias, out);
}

// Round 2
// 183.042 us; speedup vs baseline: 1.0850x; 1.0850x over previous
//
#include <hip/hip_runtime.h>
#include <hip/hip_bf16.h>
#include <stdint.h>

typedef __bf16 bf16_t;
typedef bf16_t bf16x8 __attribute__((ext_vector_type(8)));
typedef float f32x4 __attribute__((ext_vector_type(4)));

// ---------------------------------------------------------------------------
// Kernel 1: transpose + cast  x(B,C,H,W) f32  ->  xt(B,H,W,C) bf16
// ---------------------------------------------------------------------------
__global__ __launch_bounds__(256) void k_transpose(const float* __restrict__ x,
                                                   bf16_t* __restrict__ xt) {
    __shared__ __align__(16) bf16_t tile[256][66];   // +2 pad: conflict-free
    const int b = blockIdx.x >> 6;
    const int y = blockIdx.x & 63;
    const int t = threadIdx.x;

    const float* src = x + ((size_t)(b * 256) * 64 + y) * 64;  // + c*4096 + x
    const int x4 = (t & 15) * 4;   // x position (float4 granules)
    const int cs = t >> 4;         // c sub-lane (16 c per pass)
#pragma unroll
    for (int cc = 0; cc < 256; cc += 16) {
        int c = cc + cs;
        float4 v = *(const float4*)(src + (size_t)c * 4096 + x4);
        tile[c][x4 + 0] = (bf16_t)v.x;
        tile[c][x4 + 1] = (bf16_t)v.y;
        tile[c][x4 + 2] = (bf16_t)v.z;
        tile[c][x4 + 3] = (bf16_t)v.w;
    }
    __syncthreads();
    bf16_t* dst = xt + ((size_t)(b * 64 + y) * 64) * 256 + t;
#pragma unroll 8
    for (int xx = 0; xx < 64; ++xx) {
        dst[(size_t)xx * 256] = tile[t][xx];
    }
}

// ---------------------------------------------------------------------------
// Kernel 2: pack weight (O,C,3,3) f32 -> Wp2, XOR-swizzled LDS image.
// Layout: [(kb2*2 + mh)][row o 0..127][chunk js 0..7][8 elems], where
// kb2 = kk*4 + cp (K-block of 64: channels cp*64..+63 of tap kk),
// js = j ^ (o & 7)  (j = klocal/8). Flat 16 KB per (kb2,mh) image so k_dcn
// stages it with pure width-16 global_load_lds, and A-fragment ds_read_b128
// is provably <=2-way on banks (free).
// ---------------------------------------------------------------------------
__global__ __launch_bounds__(256) void k_pack_w(const float* __restrict__ w,
                                                bf16_t* __restrict__ Wp) {
    const int kb2 = blockIdx.x >> 1;    // 0..35
    const int mh  = blockIdx.x & 1;
    const int kk  = kb2 >> 2;
    const int cp  = kb2 & 3;
    const int t = threadIdx.x;
    const int o  = t & 127;
    const int jh = t >> 7;
    const int og = mh * 128 + o;
    bf16_t* base = Wp + (size_t)blockIdx.x * 8192 + o * 64;
#pragma unroll
    for (int jj = 0; jj < 4; ++jj) {
        const int j  = jh * 4 + jj;
        const int js = j ^ (o & 7);
        bf16x8 v;
#pragma unroll
        for (int e = 0; e < 8; ++e) {
            const int c = cp * 64 + j * 8 + e;
            v[e] = (bf16_t)w[(size_t)(og * 256 + c) * 9 + kk];
        }
        *(bf16x8*)(base + js * 8) = v;
    }
}

// ---------------------------------------------------------------------------
// Kernel 3: fused deformable-sample + GEMM.
// Grid 1024: b = blk&7 (XCD pin: one batch image per XCD L2), h = (blk>>3)&63,
// mh = blk>>9 (which 128-O half). 4 blocks/CU (launch_bounds 256,4).
// Per block: M=128 (O half), N=64 (full W row), K staged 64/iter (36 iters).
// 4 waves, each 32(O) x 64(px): 2x4 tiles of mfma_f32_16x16x32_bf16 x 2 Ksteps.
// ---------------------------------------------------------------------------
__global__ __launch_bounds__(256, 4) void k_dcn(
    const bf16_t* __restrict__ xt, const bf16_t* __restrict__ Wp,
    const float* __restrict__ coff, const float* __restrict__ cwm,
    const float* __restrict__ bias, float* __restrict__ out) {

    __shared__ __align__(16) bf16_t sW[128 * 64];  // 16 KB, swizzled image
    __shared__ __align__(16) bf16_t sS[64 * 64];   // 8 KB, swizzled
    __shared__ float sCW[4][64];
    __shared__ int   sCA[4][64];

    const int blk = blockIdx.x;
    const int b  = blk & 7;
    const int h  = (blk >> 3) & 63;
    const int mh = blk >> 9;
    const int t = threadIdx.x;
    const int wv = t >> 6;
    const int lane = t & 63;

    // sampling indices: 4 threads/pixel, 16 channels (32B) each
    const int p = t >> 2;
    const int q = t & 3;

    // MFMA fragment indices
    const int fr = lane & 15;
    const int quad = lane >> 4;
    const int swz = fr & 7;

    f32x4 acc[2][4] = {};

    for (int kk = 0; kk < 9; ++kk) {
        if (t < 64) {
            const int wpx = t;
            float oy = coff[((size_t)(b * 18 + kk * 2 + 0) * 64 + h) * 64 + wpx];
            float ox = coff[((size_t)(b * 18 + kk * 2 + 1) * 64 + h) * 64 + wpx];
            float m  = cwm [((size_t)(b * 9 + kk) * 64 + h) * 64 + wpx];
            float py = (float)(h - 1 + (kk / 3)) + oy;
            float px = (float)(wpx - 1 + (kk % 3)) + ox;
            float fy = floorf(py), fx = floorf(px);
            int y0 = (int)fy, x0 = (int)fx;
            int y1 = y0 + 1,  x1 = x0 + 1;
            float wy1 = py - fy, wx1 = px - fx;
            float wy0 = 1.0f - wy1, wx0 = 1.0f - wx1;
            bool vy0 = (y0 >= 0) && (y0 < 64), vy1 = (y1 >= 0) && (y1 < 64);
            bool vx0 = (x0 >= 0) && (x0 < 64), vx1 = (x1 >= 0) && (x1 < 64);
            int yc0 = min(max(y0, 0), 63), yc1 = min(max(y1, 0), 63);
            int xc0 = min(max(x0, 0), 63), xc1 = min(max(x1, 0), 63);
            const int base = b * 4096;
            sCW[0][wpx] = (vy0 && vx0) ? wy0 * wx0 * m : 0.0f;
            sCW[1][wpx] = (vy0 && vx1) ? wy0 * wx1 * m : 0.0f;
            sCW[2][wpx] = (vy1 && vx0) ? wy1 * wx0 * m : 0.0f;
            sCW[3][wpx] = (vy1 && vx1) ? wy1 * wx1 * m : 0.0f;
            sCA[0][wpx] = (base + yc0 * 64 + xc0) * 256;
            sCA[1][wpx] = (base + yc0 * 64 + xc1) * 256;
            sCA[2][wpx] = (base + yc1 * 64 + xc0) * 256;
            sCA[3][wpx] = (base + yc1 * 64 + xc1) * 256;
        }
        __syncthreads();

        for (int cp = 0; cp < 4; ++cp) {
            // ---- stage W: flat 16 KB swizzled image, async global->LDS ----
            {
                const int kb2 = kk * 4 + cp;
                const char* g = ((const char*)Wp)
                              + ((size_t)(kb2 * 2 + mh)) * 16384
                              + wv * 4096 + lane * 16;
                char* l = ((char*)sW) + wv * 4096 + lane * 16;
#pragma unroll
                for (int i = 0; i < 4; ++i) {
                    __builtin_amdgcn_global_load_lds(
                        (const __attribute__((address_space(1))) unsigned int*)(g + i * 1024),
                        (__attribute__((address_space(3))) unsigned int*)(l + i * 1024),
                        16, 0, 0);
                }
            }
            // ---- sample S: 16 contiguous channels per thread, 4 corners ----
            {
                const float w0 = sCW[0][p], w1 = sCW[1][p];
                const float w2 = sCW[2][p], w3 = sCW[3][p];
                const int a0 = sCA[0][p], a1 = sCA[1][p];
                const int a2 = sCA[2][p], a3 = sCA[3][p];
                const int cb = cp * 64 + q * 16;
                float s[16];
#pragma unroll
                for (int j = 0; j < 16; ++j) s[j] = 0.0f;
                {
                    const bf16_t* c0 = xt + a0 + cb;
                    bf16x8 u = *(const bf16x8*)c0, v = *(const bf16x8*)(c0 + 8);
#pragma unroll
                    for (int j = 0; j < 8; ++j) { s[j] += w0 * (float)u[j]; s[8 + j] += w0 * (float)v[j]; }
                }
                {
                    const bf16_t* c1 = xt + a1 + cb;
                    bf16x8 u = *(const bf16x8*)c1, v = *(const bf16x8*)(c1 + 8);
#pragma unroll
                    for (int j = 0; j < 8; ++j) { s[j] += w1 * (float)u[j]; s[8 + j] += w1 * (float)v[j]; }
                }
                {
                    const bf16_t* c2 = xt + a2 + cb;
                    bf16x8 u = *(const bf16x8*)c2, v = *(const bf16x8*)(c2 + 8);
#pragma unroll
                    for (int j = 0; j < 8; ++j) { s[j] += w2 * (float)u[j]; s[8 + j] += w2 * (float)v[j]; }
                }
                {
                    const bf16_t* c3 = xt + a3 + cb;
                    bf16x8 u = *(const bf16x8*)c3, v = *(const bf16x8*)(c3 + 8);
#pragma unroll
                    for (int j = 0; j < 8; ++j) { s[j] += w3 * (float)u[j]; s[8 + j] += w3 * (float)v[j]; }
                }
                bf16x8 o0, o1;
#pragma unroll
                for (int j = 0; j < 8; ++j) { o0[j] = (bf16_t)s[j]; o1[j] = (bf16_t)s[8 + j]; }
                const int pswz = p & 7;
                const int j0 = q * 2;
                *(bf16x8*)(sS + p * 64 + ((j0 ^ pswz) * 8))       = o0;
                *(bf16x8*)(sS + p * 64 + (((j0 + 1) ^ pswz) * 8)) = o1;
            }
            __syncthreads();   // drains vmcnt (global_load_lds) + LDS writes

            // ---- MFMA: wave = O rows [mh*128 + wv*32, +32), all 64 px ----
#pragma unroll
            for (int s = 0; s < 2; ++s) {
                const int cidx = s * 4 + quad;
                const int coff_e = (cidx ^ swz) * 8;
                bf16x8 a[2], bb[4];
#pragma unroll
                for (int mt = 0; mt < 2; ++mt)
                    a[mt] = *(const bf16x8*)(sW + (wv * 32 + mt * 16 + fr) * 64 + coff_e);
#pragma unroll
                for (int nt = 0; nt < 4; ++nt)
                    bb[nt] = *(const bf16x8*)(sS + (nt * 16 + fr) * 64 + coff_e);
#pragma unroll
                for (int mt = 0; mt < 2; ++mt)
#pragma unroll
                    for (int nt = 0; nt < 4; ++nt)
                        acc[mt][nt] = __builtin_amdgcn_mfma_f32_16x16x32_bf16(
                            a[mt], bb[nt], acc[mt][nt], 0, 0, 0);
            }
            __syncthreads();   // protect sW/sS before next staging
        }
    }

    // ---- epilogue: D layout col=lane&15 (px), row=(lane>>4)*4+r (O) ----
    const int rowq = quad * 4;
#pragma unroll
    for (int mt = 0; mt < 2; ++mt) {
#pragma unroll
        for (int r = 0; r < 4; ++r) {
            const int og = mh * 128 + wv * 32 + mt * 16 + rowq + r;
            const float bs = bias[og];
            float* op = out + ((size_t)(b * 256 + og) * 64 + h) * 64;
#pragma unroll
            for (int nt = 0; nt < 4; ++nt) {
                op[nt * 16 + fr] = acc[mt][nt][r] + bs;
            }
        }
    }
}

// ---------------------------------------------------------------------------
extern "C" void kernel_launch(void* const* d_in, const int* in_sizes, int n_in,
                              void* d_out, int out_size, void* d_ws, size_t ws_size,
                              hipStream_t stream) {
    const float* x    = (const float*)d_in[0];  // (8,256,64,64)
    const float* coff = (const float*)d_in[1];  // (8,18,64,64)
    const float* cwm  = (const float*)d_in[2];  // (8,9,64,64)
    const float* wgt  = (const float*)d_in[3];  // (256,256,3,3)
    const float* bias = (const float*)d_in[4];  // (256,)
    float* out = (float*)d_out;                 // (8,256,64,64)

    bf16_t* xt = (bf16_t*)d_ws;                  // 8*64*64*256 elems
    bf16_t* Wp = xt + (size_t)8 * 64 * 64 * 256; // 72*8192 = 589824 elems

    k_transpose<<<512,  256, 0, stream>>>(x, xt);
    k_pack_w   <<<72,   256, 0, stream>>>(wgt, Wp);
    k_dcn      <<<1024, 256, 0, stream>>>(xt, Wp, coff, cwm, bias, out);
}

// Round 3
// 165.090 us; speedup vs baseline: 1.2029x; 1.1087x over previous
//
#include <hip/hip_runtime.h>
#include <hip/hip_bf16.h>
#include <stdint.h>

typedef __bf16 bf16_t;
typedef bf16_t bf16x8 __attribute__((ext_vector_type(8)));
typedef float f32x4 __attribute__((ext_vector_type(4)));
typedef float f32x2 __attribute__((ext_vector_type(2)));

// ---------------------------------------------------------------------------
// Kernel 1: transpose + cast  x(B,C,H,W) f32  ->  xt(B,H,W,C) bf16
// ---------------------------------------------------------------------------
__global__ __launch_bounds__(256) void k_transpose(const float* __restrict__ x,
                                                   bf16_t* __restrict__ xt) {
    __shared__ __align__(16) bf16_t tile[256][66];   // +2 pad: conflict-free
    const int b = blockIdx.x >> 6;
    const int y = blockIdx.x & 63;
    const int t = threadIdx.x;

    const float* src = x + ((size_t)(b * 256) * 64 + y) * 64;  // + c*4096 + x
    const int x4 = (t & 15) * 4;   // x position (float4 granules)
    const int cs = t >> 4;         // c sub-lane (16 c per pass)
#pragma unroll
    for (int cc = 0; cc < 256; cc += 16) {
        int c = cc + cs;
        float4 v = *(const float4*)(src + (size_t)c * 4096 + x4);
        tile[c][x4 + 0] = (bf16_t)v.x;
        tile[c][x4 + 1] = (bf16_t)v.y;
        tile[c][x4 + 2] = (bf16_t)v.z;
        tile[c][x4 + 3] = (bf16_t)v.w;
    }
    __syncthreads();
    bf16_t* dst = xt + ((size_t)(b * 64 + y) * 64) * 256 + t;
#pragma unroll 8
    for (int xx = 0; xx < 64; ++xx) {
        dst[(size_t)xx * 256] = tile[t][xx];
    }
}

// ---------------------------------------------------------------------------
// Kernel 2: pack weight (O,C,3,3) f32 -> Wp, XOR-swizzled flat LDS images.
// 36 images (kb2 = kk*4+cp : channels cp*64..+63 of tap kk), each 32 KB:
//   image[o 0..255][js 0..7][8 elems], js = j ^ (o & 7), j = klocal/8.
// Flat byte offset o*128 + js*16 == the LDS offset k_dcn stages it to, so
// staging is pure width-16 global_load_lds and A-frag ds_read_b128 is <=2-way.
// ---------------------------------------------------------------------------
__global__ __launch_bounds__(256) void k_pack_w(const float* __restrict__ w,
                                                bf16_t* __restrict__ Wp) {
    const int kb2 = blockIdx.x;     // 0..35
    const int kk  = kb2 >> 2;
    const int cp  = kb2 & 3;
    const int o   = threadIdx.x;    // 0..255
    bf16_t* base = Wp + (size_t)kb2 * 16384 + o * 64;
#pragma unroll
    for (int j = 0; j < 8; ++j) {
        const int js = j ^ (o & 7);
        bf16x8 v;
#pragma unroll
        for (int e = 0; e < 8; ++e) {
            const int c = cp * 64 + j * 8 + e;
            v[e] = (bf16_t)w[(size_t)(o * 256 + c) * 9 + kk];
        }
        *(bf16x8*)(base + js * 8) = v;
    }
}

// ---------------------------------------------------------------------------
// Kernel 3: fused deformable-sample + GEMM.
// Grid 512: b = blk&7 (XCD pin), h = blk>>3. 512 threads (8 waves),
// 2 blocks/CU. Block: M=256 (ALL O - no duplicated sampling), N=64 (full W
// row), K staged 64/iter (36 iters). Wave w: O rows [w*32, +32): 2x4 tiles
// of mfma_f32_16x16x32_bf16 x 2 K-steps.
// Sampling: 8 threads/pixel x 8 channels, 4 b128 gathers per thread/iter.
// ---------------------------------------------------------------------------
__global__ __launch_bounds__(512, 4) void k_dcn(
    const bf16_t* __restrict__ xt, const bf16_t* __restrict__ Wp,
    const float* __restrict__ coff, const float* __restrict__ cwm,
    const float* __restrict__ bias, float* __restrict__ out) {

    __shared__ __align__(16) bf16_t sW[256 * 64];  // 32 KB, swizzled image
    __shared__ __align__(16) bf16_t sS[64 * 64];   // 8 KB, swizzled
    __shared__ float sCW[4][64];
    __shared__ int   sCA[4][64];

    const int blk = blockIdx.x;
    const int b  = blk & 7;
    const int h  = blk >> 3;
    const int t = threadIdx.x;
    const int wv = t >> 6;
    const int lane = t & 63;

    // sampling indices: 8 threads/pixel, 8 channels (16B) each
    const int p = t >> 3;
    const int q = t & 7;

    // MFMA fragment indices
    const int fr = lane & 15;
    const int quad = lane >> 4;
    const int swz = fr & 7;

    f32x4 acc[2][4] = {};

    for (int kk = 0; kk < 9; ++kk) {
        if (t < 64) {
            const int wpx = t;
            float oy = coff[((size_t)(b * 18 + kk * 2 + 0) * 64 + h) * 64 + wpx];
            float ox = coff[((size_t)(b * 18 + kk * 2 + 1) * 64 + h) * 64 + wpx];
            float m  = cwm [((size_t)(b * 9 + kk) * 64 + h) * 64 + wpx];
            float py = (float)(h - 1 + (kk / 3)) + oy;
            float px = (float)(wpx - 1 + (kk % 3)) + ox;
            float fy = floorf(py), fx = floorf(px);
            int y0 = (int)fy, x0 = (int)fx;
            int y1 = y0 + 1,  x1 = x0 + 1;
            float wy1 = py - fy, wx1 = px - fx;
            float wy0 = 1.0f - wy1, wx0 = 1.0f - wx1;
            bool vy0 = (y0 >= 0) && (y0 < 64), vy1 = (y1 >= 0) && (y1 < 64);
            bool vx0 = (x0 >= 0) && (x0 < 64), vx1 = (x1 >= 0) && (x1 < 64);
            int yc0 = min(max(y0, 0), 63), yc1 = min(max(y1, 0), 63);
            int xc0 = min(max(x0, 0), 63), xc1 = min(max(x1, 0), 63);
            const int base = b * 4096;
            sCW[0][wpx] = (vy0 && vx0) ? wy0 * wx0 * m : 0.0f;
            sCW[1][wpx] = (vy0 && vx1) ? wy0 * wx1 * m : 0.0f;
            sCW[2][wpx] = (vy1 && vx0) ? wy1 * wx0 * m : 0.0f;
            sCW[3][wpx] = (vy1 && vx1) ? wy1 * wx1 * m : 0.0f;
            sCA[0][wpx] = (base + yc0 * 64 + xc0) * 256;
            sCA[1][wpx] = (base + yc0 * 64 + xc1) * 256;
            sCA[2][wpx] = (base + yc1 * 64 + xc0) * 256;
            sCA[3][wpx] = (base + yc1 * 64 + xc1) * 256;
        }
        __syncthreads();

        // hoist per-kk corner params for this thread's pixel
        const float w0 = sCW[0][p], w1 = sCW[1][p];
        const float w2 = sCW[2][p], w3 = sCW[3][p];
        const bf16_t* c0 = xt + sCA[0][p] + q * 8;
        const bf16_t* c1 = xt + sCA[1][p] + q * 8;
        const bf16_t* c2 = xt + sCA[2][p] + q * 8;
        const bf16_t* c3 = xt + sCA[3][p] + q * 8;
        // sS write slot (swizzled), fixed per thread
        bf16_t* sSp = sS + p * 64 + ((q ^ (p & 7)) * 8);

        for (int cp = 0; cp < 4; ++cp) {
            // ---- stage W: flat 32 KB swizzled image, async global->LDS ----
            {
                const char* g = ((const char*)Wp)
                              + ((size_t)(kk * 4 + cp)) * 32768 + t * 16;
                char* l = ((char*)sW) + t * 16;
#pragma unroll
                for (int i = 0; i < 4; ++i) {
                    __builtin_amdgcn_global_load_lds(
                        (const __attribute__((address_space(1))) unsigned int*)(g + i * 8192),
                        (__attribute__((address_space(3))) unsigned int*)(l + i * 8192),
                        16, 0, 0);
                }
            }
            // ---- sample S: 8 contiguous channels, 4 corners, f32x2 math ----
            {
                const int cb = cp * 64;
                f32x2 s2[4] = {};
                {
                    bf16x8 v = *(const bf16x8*)(c0 + cb);
                    f32x2 ww = {w0, w0};
#pragma unroll
                    for (int j = 0; j < 4; ++j) { f32x2 f = {(float)v[2 * j], (float)v[2 * j + 1]}; s2[j] += ww * f; }
                }
                {
                    bf16x8 v = *(const bf16x8*)(c1 + cb);
                    f32x2 ww = {w1, w1};
#pragma unroll
                    for (int j = 0; j < 4; ++j) { f32x2 f = {(float)v[2 * j], (float)v[2 * j + 1]}; s2[j] += ww * f; }
                }
                {
                    bf16x8 v = *(const bf16x8*)(c2 + cb);
                    f32x2 ww = {w2, w2};
#pragma unroll
                    for (int j = 0; j < 4; ++j) { f32x2 f = {(float)v[2 * j], (float)v[2 * j + 1]}; s2[j] += ww * f; }
                }
                {
                    bf16x8 v = *(const bf16x8*)(c3 + cb);
                    f32x2 ww = {w3, w3};
#pragma unroll
                    for (int j = 0; j < 4; ++j) { f32x2 f = {(float)v[2 * j], (float)v[2 * j + 1]}; s2[j] += ww * f; }
                }
                bf16x8 ov;
#pragma unroll
                for (int j = 0; j < 4; ++j) {
                    ov[2 * j]     = (bf16_t)s2[j][0];
                    ov[2 * j + 1] = (bf16_t)s2[j][1];
                }
                *(bf16x8*)sSp = ov;
            }
            __syncthreads();   // drains vmcnt (global_load_lds) + LDS writes

            // ---- MFMA: wave = O rows [wv*32, +32), all 64 px ----
#pragma unroll
            for (int s = 0; s < 2; ++s) {
                const int cidx = s * 4 + quad;
                const int coff_e = (cidx ^ swz) * 8;
                bf16x8 a[2], bb[4];
#pragma unroll
                for (int mt = 0; mt < 2; ++mt)
                    a[mt] = *(const bf16x8*)(sW + (wv * 32 + mt * 16 + fr) * 64 + coff_e);
#pragma unroll
                for (int nt = 0; nt < 4; ++nt)
                    bb[nt] = *(const bf16x8*)(sS + (nt * 16 + fr) * 64 + coff_e);
#pragma unroll
                for (int mt = 0; mt < 2; ++mt)
#pragma unroll
                    for (int nt = 0; nt < 4; ++nt)
                        acc[mt][nt] = __builtin_amdgcn_mfma_f32_16x16x32_bf16(
                            a[mt], bb[nt], acc[mt][nt], 0, 0, 0);
            }
            __syncthreads();   // protect sW/sS before next staging
        }
    }

    // ---- epilogue: D layout col=lane&15 (px), row=(lane>>4)*4+r (O) ----
    const int rowq = quad * 4;
#pragma unroll
    for (int mt = 0; mt < 2; ++mt) {
#pragma unroll
        for (int r = 0; r < 4; ++r) {
            const int og = wv * 32 + mt * 16 + rowq + r;
            const float bs = bias[og];
            float* op = out + ((size_t)(b * 256 + og) * 64 + h) * 64;
#pragma unroll
            for (int nt = 0; nt < 4; ++nt) {
                op[nt * 16 + fr] = acc[mt][nt][r] + bs;
            }
        }
    }
}

// ---------------------------------------------------------------------------
extern "C" void kernel_launch(void* const* d_in, const int* in_sizes, int n_in,
                              void* d_out, int out_size, void* d_ws, size_t ws_size,
                              hipStream_t stream) {
    const float* x    = (const float*)d_in[0];  // (8,256,64,64)
    const float* coff = (const float*)d_in[1];  // (8,18,64,64)
    const float* cwm  = (const float*)d_in[2];  // (8,9,64,64)
    const float* wgt  = (const float*)d_in[3];  // (256,256,3,3)
    const float* bias = (const float*)d_in[4];  // (256,)
    float* out = (float*)d_out;                 // (8,256,64,64)

    bf16_t* xt = (bf16_t*)d_ws;                  // 8*64*64*256 elems
    bf16_t* Wp = xt + (size_t)8 * 64 * 64 * 256; // 36*16384 = 589824 elems

    k_transpose<<<512, 256, 0, stream>>>(x, xt);
    k_pack_w   <<<36,  256, 0, stream>>>(wgt, Wp);
    k_dcn      <<<512, 512, 0, stream>>>(xt, Wp, coff, cwm, bias, out);
}

// Round 4
// 153.868 us; speedup vs baseline: 1.2907x; 1.0729x over previous
//
#include <hip/hip_runtime.h>
#include <hip/hip_bf16.h>
#include <stdint.h>

typedef __bf16 bf16_t;
typedef bf16_t bf16x8 __attribute__((ext_vector_type(8)));
typedef float f32x4 __attribute__((ext_vector_type(4)));
typedef float f32x2 __attribute__((ext_vector_type(2)));

// ---------------------------------------------------------------------------
// Kernel 1: transpose + cast  x(B,C,H,W) f32 -> xt(B,H,W,C) bf16.
// LDS tile stored TRANSPOSED [x][c] (scalar writes, ~4-way conflicts, cheap)
// so the read+store side is fully vectorized: bf16x8 LDS reads, 1KB/wave
// coalesced global stores.
// ---------------------------------------------------------------------------
__global__ __launch_bounds__(256) void k_transpose(const float* __restrict__ x,
                                                   bf16_t* __restrict__ xt) {
    __shared__ __align__(16) bf16_t tT[64][264];   // row stride 528B (16B-mult)
    const int b = blockIdx.x >> 6;
    const int y = blockIdx.x & 63;
    const int t = threadIdx.x;

    const float* src = x + ((size_t)(b * 256) * 64 + y) * 64;  // + c*4096 + x
    const int x4 = (t & 15) * 4;
    const int cs = t >> 4;
#pragma unroll
    for (int cc = 0; cc < 256; cc += 16) {
        int c = cc + cs;
        float4 v = *(const float4*)(src + (size_t)c * 4096 + x4);
        tT[x4 + 0][c] = (bf16_t)v.x;
        tT[x4 + 1][c] = (bf16_t)v.y;
        tT[x4 + 2][c] = (bf16_t)v.z;
        tT[x4 + 3][c] = (bf16_t)v.w;
    }
    __syncthreads();
    bf16_t* dst = xt + ((size_t)(b * 64 + y) * 64) * 256;
#pragma unroll
    for (int i = 0; i < 8; ++i) {
        const int s = t + 256 * i;
        const int xx = s >> 5, cg = s & 31;
        *(bf16x8*)(dst + xx * 256 + cg * 8) = *(const bf16x8*)&tT[xx][cg * 8];
    }
}

// ---------------------------------------------------------------------------
// Kernel 2: pack weight (O,C,3,3) f32 -> Wp for DIRECT global->VGPR A-frags.
// Layout (elems): Wp[((kb2*2 + s)*256 + o)*32 + quad*8 + e], where
// kb2 = kk*4+cp, c = cp*64 + s*32 + quad*8 + e. A lane (fr,quad) of wave wv
// reads its 16B frag at base + (wv*32+mt*16+fr)*64B + quad*16B: fully
// coalesced 1KB per wave b128. Coalesced float4 reads via LDS staging.
// ---------------------------------------------------------------------------
__global__ __launch_bounds__(256) void k_pack_w(const float* __restrict__ w,
                                                bf16_t* __restrict__ Wp) {
    __shared__ float lw[8 * 2304];
    const int t = threadIdx.x;
    const int o0 = blockIdx.x * 8;
    const float4* src = (const float4*)(w + (size_t)o0 * 2304);
#pragma unroll
    for (int i = 0; i < 18; ++i) {
        ((float4*)lw)[t + 256 * i] = src[t + 256 * i];
    }
    __syncthreads();
#pragma unroll
    for (int i = 0; i < 9; ++i) {
        const int u = t + 256 * i;          // 0..2303
        const int o = u / 288, r = u - o * 288;
        const int kb2 = r >> 3, rr = r & 7;
        const int s = rr >> 2, qq = rr & 3;
        const int kk = kb2 >> 2, cp = kb2 & 3;
        bf16x8 v;
#pragma unroll
        for (int e = 0; e < 8; ++e) {
            const int c = cp * 64 + s * 32 + qq * 8 + e;
            v[e] = (bf16_t)lw[o * 2304 + c * 9 + kk];
        }
        *(bf16x8*)(Wp + ((size_t)(kb2 * 2 + s) * 256 + o0 + o) * 32 + qq * 8) = v;
    }
}

// ---------------------------------------------------------------------------
// Kernel 3: fused deformable-sample + GEMM.
// Grid 512: b = blk&7 (XCD pin), h = blk>>3; 512 threads, 2 blocks/CU.
// W (A-operand) never touches LDS: per-iter coalesced global b128 loads into
// VGPRs, prefetched one iter ahead. S (B-operand) double-buffered in LDS so
// next-iter gathers issue before this iter's MFMA. All 9 taps' corner tables
// precomputed -> exactly ONE barrier per K-iter (36 iters of K=64).
// ---------------------------------------------------------------------------
__global__ __launch_bounds__(512, 4) void k_dcn(
    const bf16_t* __restrict__ xt, const bf16_t* __restrict__ Wp,
    const float* __restrict__ coff, const float* __restrict__ cwm,
    const float* __restrict__ bias, float* __restrict__ out) {

    __shared__ __align__(16) bf16_t sS[2][64 * 64];  // 16 KB double-buffered
    __shared__ float sCW[9][4][64];                  // 9 KB corner weights
    __shared__ int   sCA[9][4][64];                  // 9 KB corner addrs

    const int blk = blockIdx.x;
    const int b  = blk & 7;
    const int h  = blk >> 3;
    const int t = threadIdx.x;
    const int wv = t >> 6;
    const int lane = t & 63;

    const int p = t >> 3;          // pixel (8 threads/pixel)
    const int q = t & 7;           // 8-channel slice

    const int fr = lane & 15;
    const int quad = lane >> 4;
    const int swz = fr & 7;

    // ---- precompute corner tables for all 9 taps ----
    for (int u = t; u < 576; u += 512) {
        const int kk = u >> 6, wpx = u & 63;
        float oy = coff[((size_t)(b * 18 + kk * 2 + 0) * 64 + h) * 64 + wpx];
        float ox = coff[((size_t)(b * 18 + kk * 2 + 1) * 64 + h) * 64 + wpx];
        float m  = cwm [((size_t)(b * 9 + kk) * 64 + h) * 64 + wpx];
        float py = (float)(h - 1 + (kk / 3)) + oy;
        float px = (float)(wpx - 1 + (kk % 3)) + ox;
        float fy = floorf(py), fx = floorf(px);
        int y0 = (int)fy, x0 = (int)fx;
        int y1 = y0 + 1,  x1 = x0 + 1;
        float wy1 = py - fy, wx1 = px - fx;
        float wy0 = 1.0f - wy1, wx0 = 1.0f - wx1;
        bool vy0 = (y0 >= 0) && (y0 < 64), vy1 = (y1 >= 0) && (y1 < 64);
        bool vx0 = (x0 >= 0) && (x0 < 64), vx1 = (x1 >= 0) && (x1 < 64);
        int yc0 = min(max(y0, 0), 63), yc1 = min(max(y1, 0), 63);
        int xc0 = min(max(x0, 0), 63), xc1 = min(max(x1, 0), 63);
        const int base = b * 4096;
        sCW[kk][0][wpx] = (vy0 && vx0) ? wy0 * wx0 * m : 0.0f;
        sCW[kk][1][wpx] = (vy0 && vx1) ? wy0 * wx1 * m : 0.0f;
        sCW[kk][2][wpx] = (vy1 && vx0) ? wy1 * wx0 * m : 0.0f;
        sCW[kk][3][wpx] = (vy1 && vx1) ? wy1 * wx1 * m : 0.0f;
        sCA[kk][0][wpx] = (base + yc0 * 64 + xc0) * 256;
        sCA[kk][1][wpx] = (base + yc0 * 64 + xc1) * 256;
        sCA[kk][2][wpx] = (base + yc1 * 64 + xc0) * 256;
        sCA[kk][3][wpx] = (base + yc1 * 64 + xc1) * 256;
    }
    __syncthreads();

    // A-frag global base (elems): + iter*16384 + s*8192 + mt*512
    const bf16_t* wA = Wp + (wv * 32 + fr) * 32 + quad * 8;
    // sS write slot (swizzled), fixed per thread
    bf16_t* sSw0 = &sS[0][0] + p * 64 + ((q ^ (p & 7)) * 8);

    f32x4 acc[2][4] = {};
    bf16x8 aC[2][2], aN[2][2];

    // sample one iter's 64ch slice for this thread into buf
    auto sample_into = [&](int iter, int buf) {
        const int kk = iter >> 2, cp = iter & 3;
        const float w0 = sCW[kk][0][p], w1 = sCW[kk][1][p];
        const float w2 = sCW[kk][2][p], w3 = sCW[kk][3][p];
        const int cb = cp * 64 + q * 8;
        bf16x8 g0 = *(const bf16x8*)(xt + sCA[kk][0][p] + cb);
        bf16x8 g1 = *(const bf16x8*)(xt + sCA[kk][1][p] + cb);
        bf16x8 g2 = *(const bf16x8*)(xt + sCA[kk][2][p] + cb);
        bf16x8 g3 = *(const bf16x8*)(xt + sCA[kk][3][p] + cb);
        f32x2 s2[4] = {};
        f32x2 W0 = {w0, w0}, W1 = {w1, w1}, W2 = {w2, w2}, W3 = {w3, w3};
#pragma unroll
        for (int j = 0; j < 4; ++j) {
            f32x2 f0 = {(float)g0[2 * j], (float)g0[2 * j + 1]};
            f32x2 f1 = {(float)g1[2 * j], (float)g1[2 * j + 1]};
            f32x2 f2 = {(float)g2[2 * j], (float)g2[2 * j + 1]};
            f32x2 f3 = {(float)g3[2 * j], (float)g3[2 * j + 1]};
            s2[j] += W0 * f0; s2[j] += W1 * f1; s2[j] += W2 * f2; s2[j] += W3 * f3;
        }
        bf16x8 ov;
#pragma unroll
        for (int j = 0; j < 4; ++j) {
            ov[2 * j]     = (bf16_t)s2[j][0];
            ov[2 * j + 1] = (bf16_t)s2[j][1];
        }
        *(bf16x8*)(sSw0 + buf * 4096) = ov;
    };

    auto do_mfma = [&](int cur) {
        const bf16_t* sb = &sS[cur][0];
#pragma unroll
        for (int s = 0; s < 2; ++s) {
            const int coffe = ((s * 4 + quad) ^ swz) * 8;
            bf16x8 bb[4];
#pragma unroll
            for (int nt = 0; nt < 4; ++nt)
                bb[nt] = *(const bf16x8*)(sb + (nt * 16 + fr) * 64 + coffe);
#pragma unroll
            for (int mt = 0; mt < 2; ++mt)
#pragma unroll
                for (int nt = 0; nt < 4; ++nt)
                    acc[mt][nt] = __builtin_amdgcn_mfma_f32_16x16x32_bf16(
                        aC[mt][s], bb[nt], acc[mt][nt], 0, 0, 0);
        }
    };

    // ---- prologue: iter 0 sample + A-load ----
    sample_into(0, 0);
    aC[0][0] = *(const bf16x8*)(wA);
    aC[0][1] = *(const bf16x8*)(wA + 8192);
    aC[1][0] = *(const bf16x8*)(wA + 512);
    aC[1][1] = *(const bf16x8*)(wA + 8192 + 512);
    __syncthreads();

    // ---- main loop: one barrier per iter ----
    for (int iter = 0; iter < 36; ++iter) {
        const int cur = iter & 1;
        if (iter < 35) {
            // prefetch next A-frags (coalesced, L2-resident)
            const bf16_t* wn = wA + (size_t)(iter + 1) * 16384;
            aN[0][0] = *(const bf16x8*)(wn);
            aN[0][1] = *(const bf16x8*)(wn + 8192);
            aN[1][0] = *(const bf16x8*)(wn + 512);
            aN[1][1] = *(const bf16x8*)(wn + 8192 + 512);
            // next-iter gathers issue before MFMA (latency hides behind it)
            sample_into(iter + 1, 1 - cur);
            do_mfma(cur);
#pragma unroll
            for (int mt = 0; mt < 2; ++mt)
#pragma unroll
                for (int s = 0; s < 2; ++s) aC[mt][s] = aN[mt][s];
        } else {
            do_mfma(cur);
        }
        __syncthreads();
    }

    // ---- epilogue: D layout col=lane&15 (px), row=(lane>>4)*4+r (O) ----
    const int rowq = quad * 4;
#pragma unroll
    for (int mt = 0; mt < 2; ++mt) {
#pragma unroll
        for (int r = 0; r < 4; ++r) {
            const int og = wv * 32 + mt * 16 + rowq + r;
            const float bs = bias[og];
            float* op = out + ((size_t)(b * 256 + og) * 64 + h) * 64;
#pragma unroll
            for (int nt = 0; nt < 4; ++nt) {
                op[nt * 16 + fr] = acc[mt][nt][r] + bs;
            }
        }
    }
}

// ---------------------------------------------------------------------------
extern "C" void kernel_launch(void* const* d_in, const int* in_sizes, int n_in,
                              void* d_out, int out_size, void* d_ws, size_t ws_size,
                              hipStream_t stream) {
    const float* x    = (const float*)d_in[0];  // (8,256,64,64)
    const float* coff = (const float*)d_in[1];  // (8,18,64,64)
    const float* cwm  = (const float*)d_in[2];  // (8,9,64,64)
    const float* wgt  = (const float*)d_in[3];  // (256,256,3,3)
    const float* bias = (const float*)d_in[4];  // (256,)
    float* out = (float*)d_out;                 // (8,256,64,64)

    bf16_t* xt = (bf16_t*)d_ws;                  // 8*64*64*256 elems
    bf16_t* Wp = xt + (size_t)8 * 64 * 64 * 256; // 36*16384 = 589824 elems

    k_transpose<<<512, 256, 0, stream>>>(x, xt);
    k_pack_w   <<<32,  256, 0, stream>>>(wgt, Wp);
    k_dcn      <<<512, 512, 0, stream>>>(xt, Wp, coff, cwm, bias, out);
}

// Round 5
// 153.299 us; speedup vs baseline: 1.2955x; 1.0037x over previous
//
#include <hip/hip_runtime.h>
#include <hip/hip_bf16.h>
#include <stdint.h>

typedef _Float16 f16_t;
typedef f16_t f16x8 __attribute__((ext_vector_type(8)));
typedef f16_t f16x2 __attribute__((ext_vector_type(2)));
typedef float f32x4 __attribute__((ext_vector_type(4)));

__device__ inline f16x2 as_f16x2(int v) {
    union { int i; f16x2 h; } u; u.i = v; return u.h;
}

// ---------------------------------------------------------------------------
// Kernel 1 (merged prep):
//  blocks 0..511  : transpose+cast x(B,C,H,W) f32 -> xt(B,H,W,C) f16
//  blocks 512..575: pack weight (O,C,3,3) f32 -> Wp f16 A-fragment layout
//    Wp[((kb2*2+s)*256 + o)*32 + quad*8 + e], c = cp*64 + s*32 + quad*8 + e,
//    kb2 = kk*4+cp. Lane (fr,quad) A-frag = one coalesced b128.
// ---------------------------------------------------------------------------
__global__ __launch_bounds__(256) void k_prep(const float* __restrict__ x,
                                              const float* __restrict__ w,
                                              f16_t* __restrict__ xt,
                                              f16_t* __restrict__ Wp) {
    __shared__ __align__(16) char smem[36864];
    const int t = threadIdx.x;
    if (blockIdx.x < 512) {
        // ---- transpose: LDS tile stored [x][c] so read+store vectorizes ----
        f16_t (*tT)[264] = (f16_t(*)[264])smem;   // row 528 B (16B mult)
        const int b = blockIdx.x >> 6;
        const int y = blockIdx.x & 63;
        const float* src = x + ((size_t)(b * 256) * 64 + y) * 64;
        const int x4 = (t & 15) * 4;
        const int cs = t >> 4;
#pragma unroll
        for (int cc = 0; cc < 256; cc += 16) {
            int c = cc + cs;
            float4 v = *(const float4*)(src + (size_t)c * 4096 + x4);
            tT[x4 + 0][c] = (f16_t)v.x;
            tT[x4 + 1][c] = (f16_t)v.y;
            tT[x4 + 2][c] = (f16_t)v.z;
            tT[x4 + 3][c] = (f16_t)v.w;
        }
        __syncthreads();
        f16_t* dst = xt + ((size_t)(b * 64 + y) * 64) * 256;
#pragma unroll
        for (int i = 0; i < 8; ++i) {
            const int s = t + 256 * i;
            const int xx = s >> 5, cg = s & 31;
            *(f16x8*)(dst + xx * 256 + cg * 8) = *(const f16x8*)&tT[xx][cg * 8];
        }
    } else {
        // ---- pack weights: 4 O rows per block ----
        float* lw = (float*)smem;                 // 4*2304 f32 = 36864 B
        const int o0 = (blockIdx.x - 512) * 4;
        const float4* src = (const float4*)(w + (size_t)o0 * 2304);
#pragma unroll
        for (int i = 0; i < 9; ++i)
            ((float4*)lw)[t + 256 * i] = src[t + 256 * i];
        __syncthreads();
#pragma unroll
        for (int i = 0; i < 5; ++i) {
            const int u = t + 256 * i;            // 0..1151
            if (u < 1152) {
                const int o = u / 288, r = u - o * 288;
                const int kb2 = r >> 3, rr = r & 7;
                const int s = rr >> 2, qq = rr & 3;
                const int kk = kb2 >> 2, cp = kb2 & 3;
                f16x8 v;
#pragma unroll
                for (int e = 0; e < 8; ++e) {
                    const int c = cp * 64 + s * 32 + qq * 8 + e;
                    v[e] = (f16_t)lw[o * 2304 + c * 9 + kk];
                }
                *(f16x8*)(Wp + ((size_t)(kb2 * 2 + s) * 256 + o0 + o) * 32 + qq * 8) = v;
            }
        }
    }
}

// ---------------------------------------------------------------------------
// Kernel 2: fused deformable-sample + GEMM, all-f16 internal.
// Grid 512: b = blk&7 (XCD pin), h = blk>>3; 512 threads, 2 blocks/CU.
// A (W) direct global->VGPR b128 prefetched 1 iter ahead; S double-buffered
// LDS; corner table = {byte_off, packed f16x2 weight} per (kk,corner,px).
// Per iter: gather loads (it+1) -> MFMA (it) -> pk_fma combine+write (it+1).
// ---------------------------------------------------------------------------
__global__ __launch_bounds__(512, 4) void k_dcn(
    const f16_t* __restrict__ xt, const f16_t* __restrict__ Wp,
    const float* __restrict__ coff, const float* __restrict__ cwm,
    const float* __restrict__ bias, float* __restrict__ out) {

    __shared__ __align__(16) f16_t sS[2][64 * 64];   // 2 x 8 KB
    __shared__ __align__(16) int2 sT[9 * 64 * 4];    // [kk][px][corner] 18 KB

    const int blk = blockIdx.x;
    const int b  = blk & 7;
    const int h  = blk >> 3;
    const int t = threadIdx.x;
    const int wv = t >> 6;
    const int lane = t & 63;

    const int p = t >> 3;          // pixel (8 threads/pixel)
    const int q = t & 7;           // 8-channel slice

    const int fr = lane & 15;
    const int quad = lane >> 4;
    const int swz = fr & 7;

    // ---- precompute corner table for all 9 taps ----
    for (int u = t; u < 576; u += 512) {
        const int kk = u >> 6, wpx = u & 63;
        float oy = coff[((size_t)(b * 18 + kk * 2 + 0) * 64 + h) * 64 + wpx];
        float ox = coff[((size_t)(b * 18 + kk * 2 + 1) * 64 + h) * 64 + wpx];
        float m  = cwm [((size_t)(b * 9 + kk) * 64 + h) * 64 + wpx];
        float py = (float)(h - 1 + (kk / 3)) + oy;
        float px = (float)(wpx - 1 + (kk % 3)) + ox;
        float fy = floorf(py), fx = floorf(px);
        int y0 = (int)fy, x0 = (int)fx;
        int y1 = y0 + 1,  x1 = x0 + 1;
        float wy1 = py - fy, wx1 = px - fx;
        float wy0 = 1.0f - wy1, wx0 = 1.0f - wx1;
        bool vy0 = (y0 >= 0) && (y0 < 64), vy1 = (y1 >= 0) && (y1 < 64);
        bool vx0 = (x0 >= 0) && (x0 < 64), vx1 = (x1 >= 0) && (x1 < 64);
        int yc0 = min(max(y0, 0), 63), yc1 = min(max(y1, 0), 63);
        int xc0 = min(max(x0, 0), 63), xc1 = min(max(x1, 0), 63);
        const int base = b * 4096;
        float cw[4];
        int   ca[4];
        cw[0] = (vy0 && vx0) ? wy0 * wx0 * m : 0.0f;
        cw[1] = (vy0 && vx1) ? wy0 * wx1 * m : 0.0f;
        cw[2] = (vy1 && vx0) ? wy1 * wx0 * m : 0.0f;
        cw[3] = (vy1 && vx1) ? wy1 * wx1 * m : 0.0f;
        ca[0] = (base + yc0 * 64 + xc0) * 512;   // byte offsets (f16)
        ca[1] = (base + yc0 * 64 + xc1) * 512;
        ca[2] = (base + yc1 * 64 + xc0) * 512;
        ca[3] = (base + yc1 * 64 + xc1) * 512;
#pragma unroll
        for (int c = 0; c < 4; ++c) {
            union { unsigned short us; f16_t hh; } cv;
            cv.hh = (f16_t)cw[c];
            int wp = (int)cv.us | ((int)cv.us << 16);
            sT[(kk * 64 + wpx) * 4 + c] = make_int2(ca[c], wp);
        }
    }
    __syncthreads();

    // A-frag global base (elems): + it*16384 + s*8192 + mt*512
    const f16_t* wA = Wp + (wv * 32 + fr) * 32 + quad * 8;
    // sS write slots (swizzled), fixed per thread
    f16_t* sw0 = &sS[0][p * 64 + ((q ^ (p & 7)) * 8)];
    f16_t* sw1 = sw0 + 4096;
    const int qb = q * 16;                       // byte offset of ch slice

    f32x4 acc[2][4] = {};
    f16x8 aC[2][2], aN[2][2];

    auto loadA = [&](int it, f16x8 (&a)[2][2]) {
        const f16_t* wn = wA + (size_t)it * 16384;
        a[0][0] = *(const f16x8*)(wn);
        a[0][1] = *(const f16x8*)(wn + 8192);
        a[1][0] = *(const f16x8*)(wn + 512);
        a[1][1] = *(const f16x8*)(wn + 8192 + 512);
    };

    auto do_mfma = [&](int cur) {
        const f16_t* sb = &sS[cur][0];
#pragma unroll
        for (int s = 0; s < 2; ++s) {
            const int coffe = ((s * 4 + quad) ^ swz) * 8;
            f16x8 bb[4];
#pragma unroll
            for (int nt = 0; nt < 4; ++nt)
                bb[nt] = *(const f16x8*)(sb + (nt * 16 + fr) * 64 + coffe);
#pragma unroll
            for (int mt = 0; mt < 2; ++mt)
#pragma unroll
                for (int nt = 0; nt < 4; ++nt)
                    acc[mt][nt] = __builtin_amdgcn_mfma_f32_16x16x32_f16(
                        aC[mt][s], bb[nt], acc[mt][nt], 0, 0, 0);
        }
    };

    // ---- prologue: sample iter 0 into buf 0, load A(0) ----
    {
        const int2* e = &sT[p * 4];              // kk = 0
        int2 e0 = e[0], e1 = e[1], e2 = e[2], e3 = e[3];
        const char* xb = (const char*)xt;
        f16x8 g0 = *(const f16x8*)(xb + (e0.x + qb));
        f16x8 g1 = *(const f16x8*)(xb + (e1.x + qb));
        f16x8 g2 = *(const f16x8*)(xb + (e2.x + qb));
        f16x8 g3 = *(const f16x8*)(xb + (e3.x + qb));
        f16x2 w0 = as_f16x2(e0.y), w1 = as_f16x2(e1.y);
        f16x2 w2 = as_f16x2(e2.y), w3 = as_f16x2(e3.y);
        const f16x2* g0p = (const f16x2*)&g0;
        const f16x2* g1p = (const f16x2*)&g1;
        const f16x2* g2p = (const f16x2*)&g2;
        const f16x2* g3p = (const f16x2*)&g3;
        f16x8 ov; f16x2* op = (f16x2*)&ov;
#pragma unroll
        for (int j = 0; j < 4; ++j)
            op[j] = g0p[j] * w0 + g1p[j] * w1 + g2p[j] * w2 + g3p[j] * w3;
        *(f16x8*)sw0 = ov;
    }
    loadA(0, aC);
    __syncthreads();

    // ---- main loop: one barrier per iter ----
#pragma unroll 2
    for (int it = 0; it < 36; ++it) {
        const int cur = it & 1;
        if (it < 35) {
            const int nx = it + 1;
            const int kk = nx >> 2, cp = nx & 3;
            // gather-load phase for it+1 (issue before MFMA)
            const int2* e = &sT[(kk * 64 + p) * 4];
            int2 e0 = e[0], e1 = e[1], e2 = e[2], e3 = e[3];
            const int cb = cp * 128 + qb;
            const char* xb = (const char*)xt;
            f16x8 g0 = *(const f16x8*)(xb + (e0.x + cb));
            f16x8 g1 = *(const f16x8*)(xb + (e1.x + cb));
            f16x8 g2 = *(const f16x8*)(xb + (e2.x + cb));
            f16x8 g3 = *(const f16x8*)(xb + (e3.x + cb));
            loadA(nx, aN);
            // MFMA for it (independent of gathers)
            do_mfma(cur);
            // combine phase for it+1
            f16x2 w0 = as_f16x2(e0.y), w1 = as_f16x2(e1.y);
            f16x2 w2 = as_f16x2(e2.y), w3 = as_f16x2(e3.y);
            const f16x2* g0p = (const f16x2*)&g0;
            const f16x2* g1p = (const f16x2*)&g1;
            const f16x2* g2p = (const f16x2*)&g2;
            const f16x2* g3p = (const f16x2*)&g3;
            f16x8 ov; f16x2* op = (f16x2*)&ov;
#pragma unroll
            for (int j = 0; j < 4; ++j)
                op[j] = g0p[j] * w0 + g1p[j] * w1 + g2p[j] * w2 + g3p[j] * w3;
            *(f16x8*)(cur ? sw0 : sw1) = ov;
#pragma unroll
            for (int mt = 0; mt < 2; ++mt)
#pragma unroll
                for (int s = 0; s < 2; ++s) aC[mt][s] = aN[mt][s];
        } else {
            do_mfma(cur);
        }
        __syncthreads();
    }

    // ---- epilogue: D layout col=lane&15 (px), row=(lane>>4)*4+r (O) ----
    const int rowq = quad * 4;
#pragma unroll
    for (int mt = 0; mt < 2; ++mt) {
#pragma unroll
        for (int r = 0; r < 4; ++r) {
            const int og = wv * 32 + mt * 16 + rowq + r;
            const float bs = bias[og];
            float* opn = out + ((size_t)(b * 256 + og) * 64 + h) * 64;
#pragma unroll
            for (int nt = 0; nt < 4; ++nt) {
                opn[nt * 16 + fr] = acc[mt][nt][r] + bs;
            }
        }
    }
}

// ---------------------------------------------------------------------------
extern "C" void kernel_launch(void* const* d_in, const int* in_sizes, int n_in,
                              void* d_out, int out_size, void* d_ws, size_t ws_size,
                              hipStream_t stream) {
    const float* x    = (const float*)d_in[0];  // (8,256,64,64)
    const float* coff = (const float*)d_in[1];  // (8,18,64,64)
    const float* cwm  = (const float*)d_in[2];  // (8,9,64,64)
    const float* wgt  = (const float*)d_in[3];  // (256,256,3,3)
    const float* bias = (const float*)d_in[4];  // (256,)
    float* out = (float*)d_out;                 // (8,256,64,64)

    f16_t* xt = (f16_t*)d_ws;                   // 8*64*64*256 elems
    f16_t* Wp = xt + (size_t)8 * 64 * 64 * 256; // 36*16384 elems

    k_prep<<<576, 256, 0, stream>>>(x, wgt, xt, Wp);
    k_dcn <<<512, 512, 0, stream>>>(xt, Wp, coff, cwm, bias, out);
}